// Round 1
// baseline (265.980 us; speedup 1.0000x reference)
//
#include <hip/hip_runtime.h>

typedef unsigned short u16;
typedef __attribute__((ext_vector_type(4))) float f32x4;
typedef __attribute__((ext_vector_type(8))) short bf16x8;

__device__ __forceinline__ u16 f2bf(float f) {
  unsigned u = __float_as_uint(f);
  u += 0x7FFFu + ((u >> 16) & 1u);
  return (u16)(u >> 16);
}
__device__ __forceinline__ float bf2f(u16 v) {
  return __uint_as_float(((unsigned)v) << 16);
}

// ---------------- convert fp32 -> bf16 ----------------
__global__ __launch_bounds__(256) void convert_f32_bf16(const float* __restrict__ in,
                                                        u16* __restrict__ out, int n) {
  int i = (blockIdx.x * 256 + threadIdx.x) * 4;
  if (i >= n) return;
  float4 v = *(const float4*)&in[i];
  out[i + 0] = f2bf(v.x);
  out[i + 1] = f2bf(v.y);
  out[i + 2] = f2bf(v.z);
  out[i + 3] = f2bf(v.w);
}

// ---------------- transpose fp32 (R x C) -> bf16 (C x R) ----------------
__global__ __launch_bounds__(256) void transpose_f32_bf16(const float* __restrict__ in,
                                                          u16* __restrict__ out,
                                                          int R, int C) {
  __shared__ float tile[32][33];
  int c0 = blockIdx.x * 32, r0 = blockIdx.y * 32;
  int tx = threadIdx.x, ty = threadIdx.y;
  for (int j = 0; j < 32; j += 8)
    tile[ty + j][tx] = in[(size_t)(r0 + ty + j) * C + c0 + tx];
  __syncthreads();
  for (int j = 0; j < 32; j += 8)
    out[(size_t)(c0 + ty + j) * R + r0 + tx] = f2bf(tile[tx][ty + j]);
}

// ---------------- transpose bf16 (R x C, ld) -> bf16 (C x R) ----------------
__global__ __launch_bounds__(256) void transpose_bf16(const u16* __restrict__ in, int ld_in,
                                                      u16* __restrict__ out, int R, int C) {
  __shared__ u16 tile[32][33];
  int c0 = blockIdx.x * 32, r0 = blockIdx.y * 32;
  int tx = threadIdx.x, ty = threadIdx.y;
  for (int j = 0; j < 32; j += 8)
    tile[ty + j][tx] = in[(size_t)(r0 + ty + j) * ld_in + c0 + tx];
  __syncthreads();
  for (int j = 0; j < 32; j += 8)
    out[(size_t)(c0 + ty + j) * R + r0 + tx] = tile[tx][ty + j];
}

// ---------------- GEMM: C(MxN) = A(MxK,bf16) @ BT(NxK,bf16) ----------------
// 128x128 tile, BK=32, 4 waves (2x2), wave tile 64x64 = 4x4 MFMA 16x16x32.
template <bool F32OUT>
__global__ __launch_bounds__(256) void gemm_bt(const u16* __restrict__ A,
                                               const u16* __restrict__ BT,
                                               void* __restrict__ Cout,
                                               int M, int N, int K) {
  const int bn = blockIdx.x * 128, bm = blockIdx.y * 128;
  const int tid = threadIdx.x;
  const int wid = tid >> 6, lane = tid & 63;
  const int wr = wid >> 1, wc = wid & 1;
  const int lrow = lane & 15, lk = (lane >> 4) << 3;  // 0,8,16,24

  __shared__ __align__(16) u16 As[128][40];
  __shared__ __align__(16) u16 Bs[128][40];

  f32x4 acc[4][4] = {};

  for (int k0 = 0; k0 < K; k0 += 32) {
#pragma unroll
    for (int i = 0; i < 2; ++i) {
      int idx = tid * 2 + i;
      int r = idx >> 2, c = (idx & 3) << 3;
      *(bf16x8*)&As[r][c] = *(const bf16x8*)&A[(size_t)(bm + r) * K + k0 + c];
      *(bf16x8*)&Bs[r][c] = *(const bf16x8*)&BT[(size_t)(bn + r) * K + k0 + c];
    }
    __syncthreads();
    bf16x8 af[4], bf[4];
#pragma unroll
    for (int m = 0; m < 4; ++m) af[m] = *(const bf16x8*)&As[wr * 64 + m * 16 + lrow][lk];
#pragma unroll
    for (int n = 0; n < 4; ++n) bf[n] = *(const bf16x8*)&Bs[wc * 64 + n * 16 + lrow][lk];
#pragma unroll
    for (int m = 0; m < 4; ++m)
#pragma unroll
      for (int n = 0; n < 4; ++n)
        acc[m][n] = __builtin_amdgcn_mfma_f32_16x16x32_bf16(af[m], bf[n], acc[m][n], 0, 0, 0);
    __syncthreads();
  }

#pragma unroll
  for (int m = 0; m < 4; ++m) {
    int row0 = bm + wr * 64 + m * 16 + ((lane >> 4) << 2);
#pragma unroll
    for (int n = 0; n < 4; ++n) {
      int col = bn + wc * 64 + n * 16 + lrow;
#pragma unroll
      for (int r = 0; r < 4; ++r) {
        if constexpr (F32OUT)
          ((float*)Cout)[(size_t)(row0 + r) * N + col] = acc[m][n][r];
        else
          ((u16*)Cout)[(size_t)(row0 + r) * N + col] = f2bf(acc[m][n][r]);
      }
    }
  }
}

// ---------------- RoPE in-place on QKV cols [0, 2304) ----------------
__global__ __launch_bounds__(256) void rope_kernel(u16* __restrict__ QKV,
                                                   const float* __restrict__ cosT,
                                                   const float* __restrict__ sinT) {
  int idx = blockIdx.x * 256 + threadIdx.x;  // 2048 * 1152 threads
  if (idx >= 2048 * 1152) return;
  int row = idx / 1152, p = idx - row * 1152;
  int col = p * 2;
  size_t off = (size_t)row * 2560 + col;
  float t0 = bf2f(QKV[off]), t1 = bf2f(QKV[off + 1]);
  int i = (col & 63) >> 1;
  float c = cosT[row * 32 + i], s = sinT[row * 32 + i];
  QKV[off] = f2bf(t0 * c - t1 * s);
  QKV[off + 1] = f2bf(t0 * s + t1 * c);
}

// ---------------- flash attention ----------------
// grid: (H=32, S/64=32). 4 waves/block, wave w owns q rows qb*64+w*16 .. +15.
__global__ __launch_bounds__(256) void attn_kernel(const u16* __restrict__ QKV,
                                                   const u16* __restrict__ VT,
                                                   u16* __restrict__ attn_out) {
  const int S = 2048;
  const int h = blockIdx.x, qb = blockIdx.y;
  const int tid = threadIdx.x, w = tid >> 6, lane = tid & 63;
  const int lrow = lane & 15, lk = (lane >> 4) << 3;
  const int kh = h >> 3;  // N_REP = 8
  const int q0 = qb * 64 + w * 16;

  __shared__ __align__(16) u16 Ks[32][72];
  __shared__ __align__(16) u16 Vs[64][40];
  __shared__ __align__(16) u16 Ps[4][16][40];

  // hoisted Q fragments (A = Q 16x64, two K=32 halves)
  bf16x8 qf[2];
  {
    size_t base = (size_t)(q0 + lrow) * 2560 + h * 64;
    qf[0] = *(const bf16x8*)&QKV[base + lk];
    qf[1] = *(const bf16x8*)&QKV[base + 32 + lk];
  }

  f32x4 acc[4] = {};
  float m[4], lsum[4];
#pragma unroll
  for (int r = 0; r < 4; ++r) { m[r] = -3e30f; lsum[r] = 0.f; }

  const int kend = qb * 64 + 64;
  for (int kb = 0; kb < kend; kb += 32) {
    {
      int r = tid >> 3, c = (tid & 7) << 3;
      *(bf16x8*)&Ks[r][c] = *(const bf16x8*)&QKV[(size_t)(kb + r) * 2560 + 2048 + kh * 64 + c];
      int r2 = tid >> 2, c2 = (tid & 3) << 3;
      *(bf16x8*)&Vs[r2][c2] = *(const bf16x8*)&VT[(size_t)(kh * 64 + r2) * S + kb + c2];
    }
    __syncthreads();

    // QK^T: two 16x16 score tiles (keys kb+c*16 .. +15)
    f32x4 sc[2] = {};
#pragma unroll
    for (int c = 0; c < 2; ++c) {
      bf16x8 kf0 = *(const bf16x8*)&Ks[c * 16 + lrow][lk];
      bf16x8 kf1 = *(const bf16x8*)&Ks[c * 16 + lrow][32 + lk];
      sc[c] = __builtin_amdgcn_mfma_f32_16x16x32_bf16(qf[0], kf0, sc[c], 0, 0, 0);
      sc[c] = __builtin_amdgcn_mfma_f32_16x16x32_bf16(qf[1], kf1, sc[c], 0, 0, 0);
    }

    // online softmax (rows: q = q0 + (lane>>4)*4 + r ; cols: key = kb + c*16 + (lane&15))
    float pv0[4], pv1[4];
#pragma unroll
    for (int r = 0; r < 4; ++r) {
      int q = q0 + ((lane >> 4) << 2) + r;
      float s0 = sc[0][r] * 0.125f;
      float s1 = sc[1][r] * 0.125f;
      if (kb + lrow > q) s0 = -30000.f;
      if (kb + 16 + lrow > q) s1 = -30000.f;
      float mx = fmaxf(s0, s1);
#pragma unroll
      for (int off = 1; off < 16; off <<= 1) mx = fmaxf(mx, __shfl_xor(mx, off, 64));
      float nm = fmaxf(m[r], mx);
      float p0 = __expf(s0 - nm);
      float p1 = __expf(s1 - nm);
      float f = __expf(m[r] - nm);
      float rs = p0 + p1;
#pragma unroll
      for (int off = 1; off < 16; off <<= 1) rs += __shfl_xor(rs, off, 64);
      lsum[r] = lsum[r] * f + rs;
      m[r] = nm;
#pragma unroll
      for (int dt = 0; dt < 4; ++dt) acc[dt][r] *= f;
      pv0[r] = p0; pv1[r] = p1;
    }

    // P -> per-wave LDS (bf16), refragment for PV
#pragma unroll
    for (int r = 0; r < 4; ++r) {
      int pr = ((lane >> 4) << 2) + r;
      Ps[w][pr][lrow] = f2bf(pv0[r]);
      Ps[w][pr][16 + lrow] = f2bf(pv1[r]);
    }
    bf16x8 pa = *(const bf16x8*)&Ps[w][lrow][lk];
#pragma unroll
    for (int dt = 0; dt < 4; ++dt) {
      bf16x8 vb = *(const bf16x8*)&Vs[dt * 16 + lrow][lk];
      acc[dt] = __builtin_amdgcn_mfma_f32_16x16x32_bf16(pa, vb, acc[dt], 0, 0, 0);
    }
    __syncthreads();
  }

  // epilogue: normalize, write bf16
#pragma unroll
  for (int dt = 0; dt < 4; ++dt)
#pragma unroll
    for (int r = 0; r < 4; ++r) {
      int q = q0 + ((lane >> 4) << 2) + r;
      attn_out[(size_t)q * 2048 + h * 64 + dt * 16 + lrow] = f2bf(acc[dt][r] / lsum[r]);
    }
}

extern "C" void kernel_launch(void* const* d_in, const int* in_sizes, int n_in,
                              void* d_out, int out_size, void* d_ws, size_t ws_size,
                              hipStream_t stream) {
  const float* x = (const float*)d_in[0];
  const float* fcos = (const float*)d_in[1];
  const float* fsin = (const float*)d_in[2];
  // d_in[3] = mask (unused; causal handled analytically)
  const float* wq = (const float*)d_in[4];
  const float* wk = (const float*)d_in[5];
  const float* wv = (const float*)d_in[6];
  const float* wo = (const float*)d_in[7];

  char* ws = (char*)d_ws;
  u16* xb    = (u16*)(ws);                    // 8 MB (reused as attn later)
  u16* wqkvT = (u16*)(ws + (8u << 20));       // 10 MB
  u16* woT   = (u16*)(ws + (18u << 20));      // 8 MB
  u16* QKV   = (u16*)(ws + (26u << 20));      // 10 MB
  u16* VT    = (u16*)(ws + (36u << 20));      // 1 MB
  u16* attn  = xb;                            // alias: xb dead after gemm1

  dim3 tb32(32, 8);

  convert_f32_bf16<<<4096, 256, 0, stream>>>(x, xb, 2048 * 2048);
  transpose_f32_bf16<<<dim3(64, 64), tb32, 0, stream>>>(wq, wqkvT, 2048, 2048);
  transpose_f32_bf16<<<dim3(8, 64), tb32, 0, stream>>>(wk, wqkvT + (size_t)2048 * 2048, 2048, 256);
  transpose_f32_bf16<<<dim3(8, 64), tb32, 0, stream>>>(wv, wqkvT + (size_t)2304 * 2048, 2048, 256);
  transpose_f32_bf16<<<dim3(64, 64), tb32, 0, stream>>>(wo, woT, 2048, 2048);

  gemm_bt<false><<<dim3(20, 16), 256, 0, stream>>>(xb, wqkvT, QKV, 2048, 2560, 2048);

  rope_kernel<<<9216, 256, 0, stream>>>(QKV, fcos, fsin);

  transpose_bf16<<<dim3(8, 64), tb32, 0, stream>>>(QKV + 2304, 2560, VT, 2048, 256);

  attn_kernel<<<dim3(32, 32), 256, 0, stream>>>(QKV, VT, attn);

  gemm_bt<true><<<dim3(16, 16), 256, 0, stream>>>(attn, woT, d_out, 2048, 2048, 2048);
}

// Round 2
// 199.739 us; speedup vs baseline: 1.3316x; 1.3316x over previous
//
#include <hip/hip_runtime.h>

typedef unsigned short u16;
typedef __attribute__((ext_vector_type(4))) float f32x4;
typedef __attribute__((ext_vector_type(8))) short bf16x8;
typedef __attribute__((ext_vector_type(4))) unsigned short u16x4;

__device__ __forceinline__ u16 f2bf(float f) {
  unsigned u = __float_as_uint(f);
  u += 0x7FFFu + ((u >> 16) & 1u);
  return (u16)(u >> 16);
}
__device__ __forceinline__ float bf2f(u16 v) {
  return __uint_as_float(((unsigned)v) << 16);
}

// ---------------- convert fp32 -> bf16 ----------------
__global__ __launch_bounds__(256) void convert_f32_bf16(const float* __restrict__ in,
                                                        u16* __restrict__ out, int n) {
  int i = (blockIdx.x * 256 + threadIdx.x) * 4;
  if (i >= n) return;
  float4 v = *(const float4*)&in[i];
  out[i + 0] = f2bf(v.x);
  out[i + 1] = f2bf(v.y);
  out[i + 2] = f2bf(v.z);
  out[i + 3] = f2bf(v.w);
}

// ---------------- transpose fp32 (R x C) -> bf16 (C x R) ----------------
__global__ __launch_bounds__(256) void transpose_f32_bf16(const float* __restrict__ in,
                                                          u16* __restrict__ out,
                                                          int R, int C) {
  __shared__ float tile[32][33];
  int c0 = blockIdx.x * 32, r0 = blockIdx.y * 32;
  int tx = threadIdx.x, ty = threadIdx.y;
  for (int j = 0; j < 32; j += 8)
    tile[ty + j][tx] = in[(size_t)(r0 + ty + j) * C + c0 + tx];
  __syncthreads();
  for (int j = 0; j < 32; j += 8)
    out[(size_t)(c0 + ty + j) * R + r0 + tx] = f2bf(tile[tx][ty + j]);
}

// ---------------- transpose bf16 (R x C, ld) -> bf16 (C x R) ----------------
__global__ __launch_bounds__(256) void transpose_bf16(const u16* __restrict__ in, int ld_in,
                                                      u16* __restrict__ out, int R, int C) {
  __shared__ u16 tile[32][33];
  int c0 = blockIdx.x * 32, r0 = blockIdx.y * 32;
  int tx = threadIdx.x, ty = threadIdx.y;
  for (int j = 0; j < 32; j += 8)
    tile[ty + j][tx] = in[(size_t)(r0 + ty + j) * ld_in + c0 + tx];
  __syncthreads();
  for (int j = 0; j < 32; j += 8)
    out[(size_t)(c0 + ty + j) * R + r0 + tx] = tile[tx][ty + j];
}

// ---------------- GEMM: C(MxN) = A(MxK,bf16) @ BT(NxK,bf16) ----------------
template <bool F32OUT>
__global__ __launch_bounds__(256) void gemm_bt(const u16* __restrict__ A,
                                               const u16* __restrict__ BT,
                                               void* __restrict__ Cout,
                                               int M, int N, int K) {
  const int bn = blockIdx.x * 128, bm = blockIdx.y * 128;
  const int tid = threadIdx.x;
  const int wid = tid >> 6, lane = tid & 63;
  const int wr = wid >> 1, wc = wid & 1;
  const int lrow = lane & 15, lk = (lane >> 4) << 3;

  __shared__ __align__(16) u16 As[128][40];
  __shared__ __align__(16) u16 Bs[128][40];

  f32x4 acc[4][4] = {};

  for (int k0 = 0; k0 < K; k0 += 32) {
#pragma unroll
    for (int i = 0; i < 2; ++i) {
      int idx = tid * 2 + i;
      int r = idx >> 2, c = (idx & 3) << 3;
      *(bf16x8*)&As[r][c] = *(const bf16x8*)&A[(size_t)(bm + r) * K + k0 + c];
      *(bf16x8*)&Bs[r][c] = *(const bf16x8*)&BT[(size_t)(bn + r) * K + k0 + c];
    }
    __syncthreads();
    bf16x8 af[4], bfr[4];
#pragma unroll
    for (int m = 0; m < 4; ++m) af[m] = *(const bf16x8*)&As[wr * 64 + m * 16 + lrow][lk];
#pragma unroll
    for (int n = 0; n < 4; ++n) bfr[n] = *(const bf16x8*)&Bs[wc * 64 + n * 16 + lrow][lk];
#pragma unroll
    for (int m = 0; m < 4; ++m)
#pragma unroll
      for (int n = 0; n < 4; ++n)
        acc[m][n] = __builtin_amdgcn_mfma_f32_16x16x32_bf16(af[m], bfr[n], acc[m][n], 0, 0, 0);
    __syncthreads();
  }

#pragma unroll
  for (int m = 0; m < 4; ++m) {
    int row0 = bm + wr * 64 + m * 16 + ((lane >> 4) << 2);
#pragma unroll
    for (int n = 0; n < 4; ++n) {
      int col = bn + wc * 64 + n * 16 + lrow;
#pragma unroll
      for (int r = 0; r < 4; ++r) {
        if constexpr (F32OUT)
          ((float*)Cout)[(size_t)(row0 + r) * N + col] = acc[m][n][r];
        else
          ((u16*)Cout)[(size_t)(row0 + r) * N + col] = f2bf(acc[m][n][r]);
      }
    }
  }
}

// ---------------- RoPE in-place on QKV cols [0, 2304) ----------------
__global__ __launch_bounds__(256) void rope_kernel(u16* __restrict__ QKV,
                                                   const float* __restrict__ cosT,
                                                   const float* __restrict__ sinT) {
  int idx = blockIdx.x * 256 + threadIdx.x;
  if (idx >= 2048 * 1152) return;
  int row = idx / 1152, p = idx - row * 1152;
  int col = p * 2;
  size_t off = (size_t)row * 2560 + col;
  float t0 = bf2f(QKV[off]), t1 = bf2f(QKV[off + 1]);
  int i = (col & 63) >> 1;
  float c = cosT[row * 32 + i], s = sinT[row * 32 + i];
  QKV[off] = f2bf(t0 * c - t1 * s);
  QKV[off + 1] = f2bf(t0 * s + t1 * c);
}

// ---------------- flash attention v2 ----------------
// grid (H=32, 32). qb reversed so heaviest causal blocks dispatch first.
// 4 waves, wave w owns q rows qb*64 + w*16 .. +15. KVBLK = 64.
// Swapped QK^T: sc = mfma(K,Q) -> S^T[key][q], q = lane&15 -> per-lane scalar
// softmax state. Swapped PV: acc = mfma(V^T, P) -> out^T[d][q].
__global__ __launch_bounds__(256) void attn_kernel(const u16* __restrict__ QKV,
                                                   const u16* __restrict__ VT,
                                                   u16* __restrict__ attn_out) {
  const int h = blockIdx.x;
  const int qb = (int)gridDim.y - 1 - (int)blockIdx.y;
  const int tid = threadIdx.x, w = tid >> 6, lane = tid & 63;
  const int lrow = lane & 15, g = lane >> 4, lk = g << 3;
  const int kh = h >> 3;
  const int q0 = qb * 64 + w * 16;
  const int q = q0 + lrow;  // this lane's q row

  __shared__ __align__(16) u16 Ks[64][72];   // [key][d]
  __shared__ __align__(16) u16 Vs[64][72];   // [d][key]  (V^T)
  __shared__ __align__(16) u16 Ps[4][16][68]; // per wave: [q local][key]

  bf16x8 qf0, qf1;
  {
    size_t base = (size_t)q * 2560 + h * 64;
    qf0 = *(const bf16x8*)&QKV[base + lk];
    qf1 = *(const bf16x8*)&QKV[base + 32 + lk];
  }

  f32x4 acc[4] = {};
  float mrun = -3e30f, lrun = 0.f;

  const int nkb = qb + 1;
  for (int ib = 0; ib < nkb; ++ib) {
    const int kb = ib * 64;
#pragma unroll
    for (int pass = 0; pass < 2; ++pass) {
      int idx = pass * 256 + tid;
      int r = idx >> 3, c = (idx & 7) << 3;
      *(bf16x8*)&Ks[r][c] = *(const bf16x8*)&QKV[(size_t)(kb + r) * 2560 + 2048 + kh * 64 + c];
      *(bf16x8*)&Vs[r][c] = *(const bf16x8*)&VT[(size_t)(kh * 64 + r) * 2048 + kb + c];
    }
    __syncthreads();

    // QK^T (swapped): sc[t] holds S^T[key = kb+t*16+g*4+r][q]
    f32x4 sc[4];
#pragma unroll
    for (int t = 0; t < 4; ++t) {
      bf16x8 kf0 = *(const bf16x8*)&Ks[t * 16 + lrow][lk];
      bf16x8 kf1 = *(const bf16x8*)&Ks[t * 16 + lrow][32 + lk];
      f32x4 z = {};
      z = __builtin_amdgcn_mfma_f32_16x16x32_bf16(kf0, qf0, z, 0, 0, 0);
      sc[t] = __builtin_amdgcn_mfma_f32_16x16x32_bf16(kf1, qf1, z, 0, 0, 0);
    }

    // mask + scale; each lane: 16 keys for its q
    float s[16];
    const int kq = q - kb;
#pragma unroll
    for (int t = 0; t < 4; ++t)
#pragma unroll
      for (int r = 0; r < 4; ++r) {
        int key = t * 16 + (g << 2) + r;
        float v = sc[t][r] * 0.125f;
        s[t * 4 + r] = (key <= kq) ? v : -30000.f;
      }

    // row max: 15 local + 2 shfl (across g groups)
    float mx = s[0];
#pragma unroll
    for (int i = 1; i < 16; ++i) mx = fmaxf(mx, s[i]);
    mx = fmaxf(mx, __shfl_xor(mx, 16, 64));
    mx = fmaxf(mx, __shfl_xor(mx, 32, 64));
    float nm = fmaxf(mrun, mx);
    float fs = __expf(mrun - nm);
    float rs = 0.f;
#pragma unroll
    for (int i = 0; i < 16; ++i) { s[i] = __expf(s[i] - nm); rs += s[i]; }
    rs += __shfl_xor(rs, 16, 64);
    rs += __shfl_xor(rs, 32, 64);
    lrun = lrun * fs + rs;
    mrun = nm;
#pragma unroll
    for (int dt = 0; dt < 4; ++dt)
#pragma unroll
      for (int r = 0; r < 4; ++r) acc[dt][r] *= fs;

    // P -> LDS: lane owns keys t*16+g*4..+3 of row q -> 4 packed b64 writes
#pragma unroll
    for (int t = 0; t < 4; ++t) {
      u16x4 pk;
#pragma unroll
      for (int r = 0; r < 4; ++r) pk[r] = f2bf(s[t * 4 + r]);
      *(u16x4*)&Ps[w][lrow][t * 16 + (g << 2)] = pk;
    }

    bf16x8 pa0 = *(const bf16x8*)&Ps[w][lrow][lk];
    bf16x8 pa1 = *(const bf16x8*)&Ps[w][lrow][32 + lk];
#pragma unroll
    for (int dt = 0; dt < 4; ++dt) {
      bf16x8 vb0 = *(const bf16x8*)&Vs[dt * 16 + lrow][lk];
      bf16x8 vb1 = *(const bf16x8*)&Vs[dt * 16 + lrow][32 + lk];
      acc[dt] = __builtin_amdgcn_mfma_f32_16x16x32_bf16(vb0, pa0, acc[dt], 0, 0, 0);
      acc[dt] = __builtin_amdgcn_mfma_f32_16x16x32_bf16(vb1, pa1, acc[dt], 0, 0, 0);
    }
    __syncthreads();
  }

  // epilogue: out[q][d], d = dt*16 + g*4 + r ; q lane-local
  float inv = 1.f / lrun;
#pragma unroll
  for (int dt = 0; dt < 4; ++dt) {
    u16x4 o;
#pragma unroll
    for (int r = 0; r < 4; ++r) o[r] = f2bf(acc[dt][r] * inv);
    *(u16x4*)&attn_out[(size_t)q * 2048 + h * 64 + dt * 16 + (g << 2)] = o;
  }
}

extern "C" void kernel_launch(void* const* d_in, const int* in_sizes, int n_in,
                              void* d_out, int out_size, void* d_ws, size_t ws_size,
                              hipStream_t stream) {
  const float* x = (const float*)d_in[0];
  const float* fcos = (const float*)d_in[1];
  const float* fsin = (const float*)d_in[2];
  const float* wq = (const float*)d_in[4];
  const float* wk = (const float*)d_in[5];
  const float* wv = (const float*)d_in[6];
  const float* wo = (const float*)d_in[7];

  char* ws = (char*)d_ws;
  u16* xb    = (u16*)(ws);                    // 8 MB (reused as attn later)
  u16* wqkvT = (u16*)(ws + (8u << 20));       // 10 MB
  u16* woT   = (u16*)(ws + (18u << 20));      // 8 MB
  u16* QKV   = (u16*)(ws + (26u << 20));      // 10 MB
  u16* VT    = (u16*)(ws + (36u << 20));      // 1 MB
  u16* attn  = xb;

  dim3 tb32(32, 8);

  convert_f32_bf16<<<4096, 256, 0, stream>>>(x, xb, 2048 * 2048);
  transpose_f32_bf16<<<dim3(64, 64), tb32, 0, stream>>>(wq, wqkvT, 2048, 2048);
  transpose_f32_bf16<<<dim3(8, 64), tb32, 0, stream>>>(wk, wqkvT + (size_t)2048 * 2048, 2048, 256);
  transpose_f32_bf16<<<dim3(8, 64), tb32, 0, stream>>>(wv, wqkvT + (size_t)2304 * 2048, 2048, 256);
  transpose_f32_bf16<<<dim3(64, 64), tb32, 0, stream>>>(wo, woT, 2048, 2048);

  gemm_bt<false><<<dim3(20, 16), 256, 0, stream>>>(xb, wqkvT, QKV, 2048, 2560, 2048);

  rope_kernel<<<9216, 256, 0, stream>>>(QKV, fcos, fsin);

  transpose_bf16<<<dim3(8, 64), tb32, 0, stream>>>(QKV + 2304, 2560, VT, 2048, 256);

  attn_kernel<<<dim3(32, 32), 256, 0, stream>>>(QKV, VT, attn);

  gemm_bt<true><<<dim3(16, 16), 256, 0, stream>>>(attn, woT, d_out, 2048, 2048, 2048);
}

// Round 3
// 156.429 us; speedup vs baseline: 1.7003x; 1.2769x over previous
//
#include <hip/hip_runtime.h>

typedef unsigned short u16;
typedef __attribute__((ext_vector_type(4))) float f32x4;
typedef __attribute__((ext_vector_type(8))) short bf16x8;
typedef __attribute__((ext_vector_type(4))) unsigned short u16x4;

__device__ __forceinline__ u16 f2bf(float f) {
  unsigned u = __float_as_uint(f);
  u += 0x7FFFu + ((u >> 16) & 1u);
  return (u16)(u >> 16);
}
__device__ __forceinline__ float bf2f(u16 v) {
  return __uint_as_float(((unsigned)v) << 16);
}

__device__ __forceinline__ void gload_lds16(const u16* g, u16* l) {
  __builtin_amdgcn_global_load_lds((const __attribute__((address_space(1))) void*)g,
                                   (__attribute__((address_space(3))) void*)l, 16, 0, 0);
}

// ---------------- convert fp32 -> bf16 ----------------
__global__ __launch_bounds__(256) void convert_f32_bf16(const float* __restrict__ in,
                                                        u16* __restrict__ out, int n) {
  int i = (blockIdx.x * 256 + threadIdx.x) * 4;
  if (i >= n) return;
  float4 v = *(const float4*)&in[i];
  out[i + 0] = f2bf(v.x);
  out[i + 1] = f2bf(v.y);
  out[i + 2] = f2bf(v.z);
  out[i + 3] = f2bf(v.w);
}

// ---------------- transpose fp32 (R x C) -> bf16 (C x R) ----------------
__global__ __launch_bounds__(256) void transpose_f32_bf16(const float* __restrict__ in,
                                                          u16* __restrict__ out,
                                                          int R, int C) {
  __shared__ float tile[32][33];
  int c0 = blockIdx.x * 32, r0 = blockIdx.y * 32;
  int tx = threadIdx.x, ty = threadIdx.y;
  for (int j = 0; j < 32; j += 8)
    tile[ty + j][tx] = in[(size_t)(r0 + ty + j) * C + c0 + tx];
  __syncthreads();
  for (int j = 0; j < 32; j += 8)
    out[(size_t)(c0 + ty + j) * R + r0 + tx] = f2bf(tile[tx][ty + j]);
}

// ---------------- transpose bf16 (R x C, ld) -> bf16 (C x R) ----------------
__global__ __launch_bounds__(256) void transpose_bf16(const u16* __restrict__ in, int ld_in,
                                                      u16* __restrict__ out, int R, int C) {
  __shared__ u16 tile[32][33];
  int c0 = blockIdx.x * 32, r0 = blockIdx.y * 32;
  int tx = threadIdx.x, ty = threadIdx.y;
  for (int j = 0; j < 32; j += 8)
    tile[ty + j][tx] = in[(size_t)(r0 + ty + j) * ld_in + c0 + tx];
  __syncthreads();
  for (int j = 0; j < 32; j += 8)
    out[(size_t)(c0 + ty + j) * R + r0 + tx] = tile[tx][ty + j];
}

// ---------------- GEMM v2: C(MxN) = A(MxK) @ BT(NxK), bf16 MFMA ----------------
// 128x128 tile, BK=64, 4 waves (2x2). global_load_lds staging into
// double-buffered linear LDS; source-side XOR swizzle (col ^= (row&7)<<4 bytes)
// matched by swizzled ds_reads -> ~2-way banked (free). Counted vmcnt(8)
// keeps next tile's 8 loads/wave in flight across the barrier.
template <bool F32OUT>
__global__ __launch_bounds__(256) void gemm_bt(const u16* __restrict__ A,
                                               const u16* __restrict__ BT,
                                               void* __restrict__ Cout,
                                               int M, int N, int K) {
  const int bn = blockIdx.x * 128, bm = blockIdx.y * 128;
  const int tid = threadIdx.x;
  const int wid = tid >> 6, lane = tid & 63;
  const int wr = wid >> 1, wc = wid & 1;
  const int lrow = lane & 15, g = lane >> 4;

  __shared__ __align__(16) u16 As[2][128 * 64];
  __shared__ __align__(16) u16 Bs[2][128 * 64];

  // Staging: pass p covers rows p*32 + tid/8; col (u16) = swizzled
  const int srow = tid >> 3;
  const int cswz = (((tid & 7) ^ (srow & 7)) << 3);
  const u16* a_src = A + (size_t)(bm + srow) * K + cswz;
  const u16* b_src = BT + (size_t)(bn + srow) * K + cswz;

  // Read-side swizzled u16 column offsets for the two K=32 slices
  const int rsw = (lrow & 7) << 4;  // byte swizzle
  const int colsw0 = ((g * 16) ^ rsw) >> 1;
  const int colsw1 = ((64 + g * 16) ^ rsw) >> 1;

#define STAGE(buf, k0)                                                        \
  do {                                                                        \
    const u16* ap = a_src + (k0);                                             \
    const u16* bp = b_src + (k0);                                             \
    u16* ad = &As[buf][0] + tid * 8;                                          \
    u16* bd = &Bs[buf][0] + tid * 8;                                          \
    _Pragma("unroll") for (int p = 0; p < 4; ++p) {                           \
      gload_lds16(ap + (size_t)p * 32 * K, ad + p * 2048);                    \
      gload_lds16(bp + (size_t)p * 32 * K, bd + p * 2048);                    \
    }                                                                         \
  } while (0)

  f32x4 acc[4][4] = {};

  const int nt = K >> 6;  // K/64
  STAGE(0, 0);
  int cur = 0;
  for (int t = 0; t < nt; ++t) {
    if (t + 1 < nt) {
      STAGE(cur ^ 1, (t + 1) * 64);
      asm volatile("s_waitcnt vmcnt(8)" ::: "memory");
    } else {
      asm volatile("s_waitcnt vmcnt(0)" ::: "memory");
    }
    __builtin_amdgcn_s_barrier();
    asm volatile("" ::: "memory");

    bf16x8 af[4][2], bfr[4][2];
#pragma unroll
    for (int m = 0; m < 4; ++m) {
      int row = wr * 64 + m * 16 + lrow;
      af[m][0] = *(const bf16x8*)&As[cur][row * 64 + colsw0];
      af[m][1] = *(const bf16x8*)&As[cur][row * 64 + colsw1];
    }
#pragma unroll
    for (int n = 0; n < 4; ++n) {
      int row = wc * 64 + n * 16 + lrow;
      bfr[n][0] = *(const bf16x8*)&Bs[cur][row * 64 + colsw0];
      bfr[n][1] = *(const bf16x8*)&Bs[cur][row * 64 + colsw1];
    }
#pragma unroll
    for (int ks = 0; ks < 2; ++ks)
#pragma unroll
      for (int m = 0; m < 4; ++m)
#pragma unroll
        for (int n = 0; n < 4; ++n)
          acc[m][n] =
              __builtin_amdgcn_mfma_f32_16x16x32_bf16(af[m][ks], bfr[n][ks], acc[m][n], 0, 0, 0);

    asm volatile("" ::: "memory");
    __builtin_amdgcn_s_barrier();
    cur ^= 1;
  }
#undef STAGE

#pragma unroll
  for (int m = 0; m < 4; ++m) {
    int row0 = bm + wr * 64 + m * 16 + (g << 2);
#pragma unroll
    for (int n = 0; n < 4; ++n) {
      int col = bn + wc * 64 + n * 16 + lrow;
#pragma unroll
      for (int r = 0; r < 4; ++r) {
        if constexpr (F32OUT)
          ((float*)Cout)[(size_t)(row0 + r) * N + col] = acc[m][n][r];
        else
          ((u16*)Cout)[(size_t)(row0 + r) * N + col] = f2bf(acc[m][n][r]);
      }
    }
  }
}

// ---------------- RoPE in-place on QKV cols [0, 2304) ----------------
__global__ __launch_bounds__(256) void rope_kernel(u16* __restrict__ QKV,
                                                   const float* __restrict__ cosT,
                                                   const float* __restrict__ sinT) {
  int idx = blockIdx.x * 256 + threadIdx.x;
  if (idx >= 2048 * 1152) return;
  int row = idx / 1152, p = idx - row * 1152;
  int col = p * 2;
  size_t off = (size_t)row * 2560 + col;
  float t0 = bf2f(QKV[off]), t1 = bf2f(QKV[off + 1]);
  int i = (col & 63) >> 1;
  float c = cosT[row * 32 + i], s = sinT[row * 32 + i];
  QKV[off] = f2bf(t0 * c - t1 * s);
  QKV[off + 1] = f2bf(t0 * s + t1 * c);
}

// ---------------- flash attention (unchanged from round 2) ----------------
__global__ __launch_bounds__(256) void attn_kernel(const u16* __restrict__ QKV,
                                                   const u16* __restrict__ VT,
                                                   u16* __restrict__ attn_out) {
  const int h = blockIdx.x;
  const int qb = (int)gridDim.y - 1 - (int)blockIdx.y;
  const int tid = threadIdx.x, w = tid >> 6, lane = tid & 63;
  const int lrow = lane & 15, g = lane >> 4, lk = g << 3;
  const int kh = h >> 3;
  const int q0 = qb * 64 + w * 16;
  const int q = q0 + lrow;

  __shared__ __align__(16) u16 Ks[64][72];
  __shared__ __align__(16) u16 Vs[64][72];
  __shared__ __align__(16) u16 Ps[4][16][68];

  bf16x8 qf0, qf1;
  {
    size_t base = (size_t)q * 2560 + h * 64;
    qf0 = *(const bf16x8*)&QKV[base + lk];
    qf1 = *(const bf16x8*)&QKV[base + 32 + lk];
  }

  f32x4 acc[4] = {};
  float mrun = -3e30f, lrun = 0.f;

  const int nkb = qb + 1;
  for (int ib = 0; ib < nkb; ++ib) {
    const int kb = ib * 64;
#pragma unroll
    for (int pass = 0; pass < 2; ++pass) {
      int idx = pass * 256 + tid;
      int r = idx >> 3, c = (idx & 7) << 3;
      *(bf16x8*)&Ks[r][c] = *(const bf16x8*)&QKV[(size_t)(kb + r) * 2560 + 2048 + kh * 64 + c];
      *(bf16x8*)&Vs[r][c] = *(const bf16x8*)&VT[(size_t)(kh * 64 + r) * 2048 + kb + c];
    }
    __syncthreads();

    f32x4 sc[4];
#pragma unroll
    for (int t = 0; t < 4; ++t) {
      bf16x8 kf0 = *(const bf16x8*)&Ks[t * 16 + lrow][lk];
      bf16x8 kf1 = *(const bf16x8*)&Ks[t * 16 + lrow][32 + lk];
      f32x4 z = {};
      z = __builtin_amdgcn_mfma_f32_16x16x32_bf16(kf0, qf0, z, 0, 0, 0);
      sc[t] = __builtin_amdgcn_mfma_f32_16x16x32_bf16(kf1, qf1, z, 0, 0, 0);
    }

    float s[16];
    const int kq = q - kb;
#pragma unroll
    for (int t = 0; t < 4; ++t)
#pragma unroll
      for (int r = 0; r < 4; ++r) {
        int key = t * 16 + (g << 2) + r;
        float v = sc[t][r] * 0.125f;
        s[t * 4 + r] = (key <= kq) ? v : -30000.f;
      }

    float mx = s[0];
#pragma unroll
    for (int i = 1; i < 16; ++i) mx = fmaxf(mx, s[i]);
    mx = fmaxf(mx, __shfl_xor(mx, 16, 64));
    mx = fmaxf(mx, __shfl_xor(mx, 32, 64));
    float nm = fmaxf(mrun, mx);
    float fs = __expf(mrun - nm);
    float rs = 0.f;
#pragma unroll
    for (int i = 0; i < 16; ++i) { s[i] = __expf(s[i] - nm); rs += s[i]; }
    rs += __shfl_xor(rs, 16, 64);
    rs += __shfl_xor(rs, 32, 64);
    lrun = lrun * fs + rs;
    mrun = nm;
#pragma unroll
    for (int dt = 0; dt < 4; ++dt)
#pragma unroll
      for (int r = 0; r < 4; ++r) acc[dt][r] *= fs;

#pragma unroll
    for (int t = 0; t < 4; ++t) {
      u16x4 pk;
#pragma unroll
      for (int r = 0; r < 4; ++r) pk[r] = f2bf(s[t * 4 + r]);
      *(u16x4*)&Ps[w][lrow][t * 16 + (g << 2)] = pk;
    }

    bf16x8 pa0 = *(const bf16x8*)&Ps[w][lrow][lk];
    bf16x8 pa1 = *(const bf16x8*)&Ps[w][lrow][32 + lk];
#pragma unroll
    for (int dt = 0; dt < 4; ++dt) {
      bf16x8 vb0 = *(const bf16x8*)&Vs[dt * 16 + lrow][lk];
      bf16x8 vb1 = *(const bf16x8*)&Vs[dt * 16 + lrow][32 + lk];
      acc[dt] = __builtin_amdgcn_mfma_f32_16x16x32_bf16(vb0, pa0, acc[dt], 0, 0, 0);
      acc[dt] = __builtin_amdgcn_mfma_f32_16x16x32_bf16(vb1, pa1, acc[dt], 0, 0, 0);
    }
    __syncthreads();
  }

  float inv = 1.f / lrun;
#pragma unroll
  for (int dt = 0; dt < 4; ++dt) {
    u16x4 o;
#pragma unroll
    for (int r = 0; r < 4; ++r) o[r] = f2bf(acc[dt][r] * inv);
    *(u16x4*)&attn_out[(size_t)q * 2048 + h * 64 + dt * 16 + (g << 2)] = o;
  }
}

extern "C" void kernel_launch(void* const* d_in, const int* in_sizes, int n_in,
                              void* d_out, int out_size, void* d_ws, size_t ws_size,
                              hipStream_t stream) {
  const float* x = (const float*)d_in[0];
  const float* fcos = (const float*)d_in[1];
  const float* fsin = (const float*)d_in[2];
  const float* wq = (const float*)d_in[4];
  const float* wk = (const float*)d_in[5];
  const float* wv = (const float*)d_in[6];
  const float* wo = (const float*)d_in[7];

  char* ws = (char*)d_ws;
  u16* xb    = (u16*)(ws);                    // 8 MB (reused as attn later)
  u16* wqkvT = (u16*)(ws + (8u << 20));       // 10 MB
  u16* woT   = (u16*)(ws + (18u << 20));      // 8 MB
  u16* QKV   = (u16*)(ws + (26u << 20));      // 10 MB
  u16* VT    = (u16*)(ws + (36u << 20));      // 1 MB
  u16* attn  = xb;

  dim3 tb32(32, 8);

  convert_f32_bf16<<<4096, 256, 0, stream>>>(x, xb, 2048 * 2048);
  transpose_f32_bf16<<<dim3(64, 64), tb32, 0, stream>>>(wq, wqkvT, 2048, 2048);
  transpose_f32_bf16<<<dim3(8, 64), tb32, 0, stream>>>(wk, wqkvT + (size_t)2048 * 2048, 2048, 256);
  transpose_f32_bf16<<<dim3(8, 64), tb32, 0, stream>>>(wv, wqkvT + (size_t)2304 * 2048, 2048, 256);
  transpose_f32_bf16<<<dim3(64, 64), tb32, 0, stream>>>(wo, woT, 2048, 2048);

  gemm_bt<false><<<dim3(20, 16), 256, 0, stream>>>(xb, wqkvT, QKV, 2048, 2560, 2048);

  rope_kernel<<<9216, 256, 0, stream>>>(QKV, fcos, fsin);

  transpose_bf16<<<dim3(8, 64), tb32, 0, stream>>>(QKV + 2304, 2560, VT, 2048, 256);

  attn_kernel<<<dim3(32, 32), 256, 0, stream>>>(QKV, VT, attn);

  gemm_bt<true><<<dim3(16, 16), 256, 0, stream>>>(attn, woT, d_out, 2048, 2048, 2048);
}

// Round 4
// 152.817 us; speedup vs baseline: 1.7405x; 1.0236x over previous
//
#include <hip/hip_runtime.h>

typedef unsigned short u16;
typedef __attribute__((ext_vector_type(4))) float f32x4;
typedef __attribute__((ext_vector_type(8))) short bf16x8;
typedef __attribute__((ext_vector_type(4))) unsigned short u16x4;

__device__ __forceinline__ u16 f2bf(float f) {
  unsigned u = __float_as_uint(f);
  u += 0x7FFFu + ((u >> 16) & 1u);
  return (u16)(u >> 16);
}
__device__ __forceinline__ float bf2f(u16 v) {
  return __uint_as_float(((unsigned)v) << 16);
}

__device__ __forceinline__ void gload_lds16(const u16* g, u16* l) {
  __builtin_amdgcn_global_load_lds((const __attribute__((address_space(1))) void*)g,
                                   (__attribute__((address_space(3))) void*)l, 16, 0, 0);
}

__device__ __forceinline__ unsigned cvt_pk_bf16(float lo, float hi) {
  unsigned r;
  asm("v_cvt_pk_bf16_f32 %0, %1, %2" : "=v"(r) : "v"(lo), "v"(hi));
  return r;
}

// ---------------- convert fp32 -> bf16 ----------------
__global__ __launch_bounds__(256) void convert_f32_bf16(const float* __restrict__ in,
                                                        u16* __restrict__ out, int n) {
  int i = (blockIdx.x * 256 + threadIdx.x) * 4;
  if (i >= n) return;
  float4 v = *(const float4*)&in[i];
  out[i + 0] = f2bf(v.x);
  out[i + 1] = f2bf(v.y);
  out[i + 2] = f2bf(v.z);
  out[i + 3] = f2bf(v.w);
}

// ---------------- transpose fp32 (R x C) -> bf16 (C x R) ----------------
__global__ __launch_bounds__(256) void transpose_f32_bf16(const float* __restrict__ in,
                                                          u16* __restrict__ out,
                                                          int R, int C) {
  __shared__ float tile[32][33];
  int c0 = blockIdx.x * 32, r0 = blockIdx.y * 32;
  int tx = threadIdx.x, ty = threadIdx.y;
  for (int j = 0; j < 32; j += 8)
    tile[ty + j][tx] = in[(size_t)(r0 + ty + j) * C + c0 + tx];
  __syncthreads();
  for (int j = 0; j < 32; j += 8)
    out[(size_t)(c0 + ty + j) * R + r0 + tx] = f2bf(tile[tx][ty + j]);
}

// ---------------- transpose bf16 (R x C, ld) -> bf16 (C x R) ----------------
__global__ __launch_bounds__(256) void transpose_bf16(const u16* __restrict__ in, int ld_in,
                                                      u16* __restrict__ out, int R, int C) {
  __shared__ u16 tile[32][33];
  int c0 = blockIdx.x * 32, r0 = blockIdx.y * 32;
  int tx = threadIdx.x, ty = threadIdx.y;
  for (int j = 0; j < 32; j += 8)
    tile[ty + j][tx] = in[(size_t)(r0 + ty + j) * ld_in + c0 + tx];
  __syncthreads();
  for (int j = 0; j < 32; j += 8)
    out[(size_t)(c0 + ty + j) * R + r0 + tx] = tile[tx][ty + j];
}

// ---------------- GEMM v2 (unchanged from round 3) ----------------
template <bool F32OUT>
__global__ __launch_bounds__(256) void gemm_bt(const u16* __restrict__ A,
                                               const u16* __restrict__ BT,
                                               void* __restrict__ Cout,
                                               int M, int N, int K) {
  const int bn = blockIdx.x * 128, bm = blockIdx.y * 128;
  const int tid = threadIdx.x;
  const int wid = tid >> 6, lane = tid & 63;
  const int wr = wid >> 1, wc = wid & 1;
  const int lrow = lane & 15, g = lane >> 4;

  __shared__ __align__(16) u16 As[2][128 * 64];
  __shared__ __align__(16) u16 Bs[2][128 * 64];

  const int srow = tid >> 3;
  const int cswz = (((tid & 7) ^ (srow & 7)) << 3);
  const u16* a_src = A + (size_t)(bm + srow) * K + cswz;
  const u16* b_src = BT + (size_t)(bn + srow) * K + cswz;

  const int rsw = (lrow & 7) << 4;
  const int colsw0 = ((g * 16) ^ rsw) >> 1;
  const int colsw1 = ((64 + g * 16) ^ rsw) >> 1;

#define STAGE(buf, k0)                                                        \
  do {                                                                        \
    const u16* ap = a_src + (k0);                                             \
    const u16* bp = b_src + (k0);                                             \
    u16* ad = &As[buf][0] + tid * 8;                                          \
    u16* bd = &Bs[buf][0] + tid * 8;                                          \
    _Pragma("unroll") for (int p = 0; p < 4; ++p) {                           \
      gload_lds16(ap + (size_t)p * 32 * K, ad + p * 2048);                    \
      gload_lds16(bp + (size_t)p * 32 * K, bd + p * 2048);                    \
    }                                                                         \
  } while (0)

  f32x4 acc[4][4] = {};

  const int nt = K >> 6;
  STAGE(0, 0);
  int cur = 0;
  for (int t = 0; t < nt; ++t) {
    if (t + 1 < nt) {
      STAGE(cur ^ 1, (t + 1) * 64);
      asm volatile("s_waitcnt vmcnt(8)" ::: "memory");
    } else {
      asm volatile("s_waitcnt vmcnt(0)" ::: "memory");
    }
    __builtin_amdgcn_s_barrier();
    asm volatile("" ::: "memory");

    bf16x8 af[4][2], bfr[4][2];
#pragma unroll
    for (int m = 0; m < 4; ++m) {
      int row = wr * 64 + m * 16 + lrow;
      af[m][0] = *(const bf16x8*)&As[cur][row * 64 + colsw0];
      af[m][1] = *(const bf16x8*)&As[cur][row * 64 + colsw1];
    }
#pragma unroll
    for (int n = 0; n < 4; ++n) {
      int row = wc * 64 + n * 16 + lrow;
      bfr[n][0] = *(const bf16x8*)&Bs[cur][row * 64 + colsw0];
      bfr[n][1] = *(const bf16x8*)&Bs[cur][row * 64 + colsw1];
    }
#pragma unroll
    for (int ks = 0; ks < 2; ++ks)
#pragma unroll
      for (int m = 0; m < 4; ++m)
#pragma unroll
        for (int n = 0; n < 4; ++n)
          acc[m][n] =
              __builtin_amdgcn_mfma_f32_16x16x32_bf16(af[m][ks], bfr[n][ks], acc[m][n], 0, 0, 0);

    asm volatile("" ::: "memory");
    __builtin_amdgcn_s_barrier();
    cur ^= 1;
  }
#undef STAGE

#pragma unroll
  for (int m = 0; m < 4; ++m) {
    int row0 = bm + wr * 64 + m * 16 + (g << 2);
#pragma unroll
    for (int n = 0; n < 4; ++n) {
      int col = bn + wc * 64 + n * 16 + lrow;
#pragma unroll
      for (int r = 0; r < 4; ++r) {
        if constexpr (F32OUT)
          ((float*)Cout)[(size_t)(row0 + r) * N + col] = acc[m][n][r];
        else
          ((u16*)Cout)[(size_t)(row0 + r) * N + col] = f2bf(acc[m][n][r]);
      }
    }
  }
}

// ---------------- RoPE in-place on QKV cols [0, 2304) ----------------
__global__ __launch_bounds__(256) void rope_kernel(u16* __restrict__ QKV,
                                                   const float* __restrict__ cosT,
                                                   const float* __restrict__ sinT) {
  int idx = blockIdx.x * 256 + threadIdx.x;
  if (idx >= 2048 * 1152) return;
  int row = idx / 1152, p = idx - row * 1152;
  int col = p * 2;
  size_t off = (size_t)row * 2560 + col;
  float t0 = bf2f(QKV[off]), t1 = bf2f(QKV[off + 1]);
  int i = (col & 63) >> 1;
  float c = cosT[row * 32 + i], s = sinT[row * 32 + i];
  QKV[off] = f2bf(t0 * c - t1 * s);
  QKV[off + 1] = f2bf(t0 * s + t1 * c);
}

// ---------------- flash attention v3 ----------------
// KVBLK=64, double-buffered K/V via global_load_lds (lane-linear LDS dest,
// source-column XOR swizzle byte^=((row&7)<<4)), counted vmcnt(4), exp2-domain
// softmax, diag-only masking, defer-max (THR=8 log2), cvt_pk P packing.
__global__ __launch_bounds__(256) void attn_kernel(const u16* __restrict__ QKV,
                                                   const u16* __restrict__ VT,
                                                   u16* __restrict__ attn_out) {
  const int h = blockIdx.x;
  const int qb = (int)gridDim.y - 1 - (int)blockIdx.y;
  const int tid = threadIdx.x, w = tid >> 6, lane = tid & 63;
  const int lrow = lane & 15, g = lane >> 4;
  const int kh = h >> 3;
  const int q0 = qb * 64 + w * 16;
  const int q = q0 + lrow;

  __shared__ __align__(16) u16 Ks[2][64 * 64];
  __shared__ __align__(16) u16 Vs[2][64 * 64];
  __shared__ __align__(16) u16 Ps[4][16 * 64];

  // staging: wave w, pass p -> LDS rows w*16+p*8 .. +7, lane-linear 1KB block.
  // lane l covers row w*16+p*8+(l>>3), 16B chunk (l&7); source col pre-swizzled.
  const int srowl = w * 16 + (lane >> 3);               // + p*8
  const int scol = (((lane & 7) ^ (lane >> 3)) << 3);   // swizzled u16 col
  const u16* ksrc = QKV + 2048 + (size_t)kh * 64 + scol;
  const u16* vsrc = VT + (size_t)(kh * 64 + srowl) * 2048 + scol;

#define ASTAGE(buf, kb)                                                          \
  do {                                                                           \
    _Pragma("unroll") for (int p = 0; p < 2; ++p) {                              \
      gload_lds16(ksrc + (size_t)((kb) + srowl + p * 8) * 2560,                  \
                  &Ks[buf][(w * 2 + p) * 512]);                                  \
      gload_lds16(vsrc + (size_t)p * 8 * 2048 + (kb),                            \
                  &Vs[buf][(w * 2 + p) * 512]);                                  \
    }                                                                            \
  } while (0)

  // Q fragments (hoisted)
  bf16x8 qf0, qf1;
  {
    size_t base = (size_t)q * 2560 + h * 64;
    qf0 = *(const bf16x8*)&QKV[base + g * 8];
    qf1 = *(const bf16x8*)&QKV[base + 32 + g * 8];
  }

  // read-side swizzled column offsets (u16 units)
  const int swz = (lrow & 7) << 3;
  const int ca0 = (g * 8) ^ swz;
  const int ca1 = (32 + g * 8) ^ swz;

  f32x4 acc[4] = {};
  float mrun = -3e30f, lrun = 0.f;
  const float SC = 0.125f * 1.44269504088896f;  // scale * log2(e)

  const int nkb = qb + 1;
  ASTAGE(0, 0);
  int cur = 0;

  for (int ib = 0; ib < nkb; ++ib) {
    const bool last = (ib == nkb - 1);
    if (!last) {
      ASTAGE(cur ^ 1, (ib + 1) * 64);
      asm volatile("s_waitcnt vmcnt(4)" ::: "memory");
    } else {
      asm volatile("s_waitcnt vmcnt(0)" ::: "memory");
    }
    __builtin_amdgcn_s_barrier();
    asm volatile("" ::: "memory");

    const u16* Kc = &Ks[cur][0];
    const u16* Vc = &Vs[cur][0];

    // QK^T (swapped): sc4[t][r] = S^T[key = t*16+g*4+r][q]
    f32x4 sc4[4];
    __builtin_amdgcn_s_setprio(1);
#pragma unroll
    for (int t = 0; t < 4; ++t) {
      bf16x8 kf0 = *(const bf16x8*)&Kc[(t * 16 + lrow) * 64 + ca0];
      bf16x8 kf1 = *(const bf16x8*)&Kc[(t * 16 + lrow) * 64 + ca1];
      f32x4 z = {};
      z = __builtin_amdgcn_mfma_f32_16x16x32_bf16(kf0, qf0, z, 0, 0, 0);
      sc4[t] = __builtin_amdgcn_mfma_f32_16x16x32_bf16(kf1, qf1, z, 0, 0, 0);
    }
    __builtin_amdgcn_s_setprio(0);

    float s[16];
    if (last) {
      const int kq = w * 16 + lrow;
#pragma unroll
      for (int t = 0; t < 4; ++t)
#pragma unroll
        for (int r = 0; r < 4; ++r) {
          int key = t * 16 + (g << 2) + r;
          s[t * 4 + r] = (key <= kq) ? sc4[t][r] * SC : -3e4f;
        }
    } else {
#pragma unroll
      for (int t = 0; t < 4; ++t)
#pragma unroll
        for (int r = 0; r < 4; ++r) s[t * 4 + r] = sc4[t][r] * SC;
    }

    float mx = s[0];
#pragma unroll
    for (int i = 1; i < 16; ++i) mx = fmaxf(mx, s[i]);
    mx = fmaxf(mx, __shfl_xor(mx, 16, 64));
    mx = fmaxf(mx, __shfl_xor(mx, 32, 64));

    if (__any(mx > mrun + 8.f)) {  // defer-max: rescale only on real growth
      float nm = fmaxf(mrun, mx);
      float fs = exp2f(mrun - nm);
      mrun = nm;
      lrun *= fs;
#pragma unroll
      for (int dt = 0; dt < 4; ++dt)
#pragma unroll
        for (int r = 0; r < 4; ++r) acc[dt][r] *= fs;
    }

    float rs = 0.f;
#pragma unroll
    for (int i = 0; i < 16; ++i) {
      s[i] = exp2f(s[i] - mrun);
      rs += s[i];
    }
    rs += __shfl_xor(rs, 16, 64);
    rs += __shfl_xor(rs, 32, 64);
    lrun += rs;

    // P -> per-wave swizzled LDS (cvt_pk packs 2 floats/op)
    u16* pw = &Ps[w][0];
#pragma unroll
    for (int t = 0; t < 4; ++t) {
      uint2 pk;
      pk.x = cvt_pk_bf16(s[t * 4 + 0], s[t * 4 + 1]);
      pk.y = cvt_pk_bf16(s[t * 4 + 2], s[t * 4 + 3]);
      *(uint2*)&pw[lrow * 64 + ((t * 16 + (g << 2)) ^ swz)] = pk;
    }

    bf16x8 pa0 = *(const bf16x8*)&pw[lrow * 64 + ca0];
    bf16x8 pa1 = *(const bf16x8*)&pw[lrow * 64 + ca1];
    __builtin_amdgcn_s_setprio(1);
#pragma unroll
    for (int dt = 0; dt < 4; ++dt) {
      bf16x8 vb0 = *(const bf16x8*)&Vc[(dt * 16 + lrow) * 64 + ca0];
      bf16x8 vb1 = *(const bf16x8*)&Vc[(dt * 16 + lrow) * 64 + ca1];
      acc[dt] = __builtin_amdgcn_mfma_f32_16x16x32_bf16(vb0, pa0, acc[dt], 0, 0, 0);
      acc[dt] = __builtin_amdgcn_mfma_f32_16x16x32_bf16(vb1, pa1, acc[dt], 0, 0, 0);
    }
    __builtin_amdgcn_s_setprio(0);

    asm volatile("" ::: "memory");
    __builtin_amdgcn_s_barrier();
    cur ^= 1;
  }
#undef ASTAGE

  float inv = 1.f / lrun;
#pragma unroll
  for (int dt = 0; dt < 4; ++dt) {
    u16x4 o;
#pragma unroll
    for (int r = 0; r < 4; ++r) o[r] = f2bf(acc[dt][r] * inv);
    *(u16x4*)&attn_out[(size_t)q * 2048 + h * 64 + dt * 16 + (g << 2)] = o;
  }
}

extern "C" void kernel_launch(void* const* d_in, const int* in_sizes, int n_in,
                              void* d_out, int out_size, void* d_ws, size_t ws_size,
                              hipStream_t stream) {
  const float* x = (const float*)d_in[0];
  const float* fcos = (const float*)d_in[1];
  const float* fsin = (const float*)d_in[2];
  const float* wq = (const float*)d_in[4];
  const float* wk = (const float*)d_in[5];
  const float* wv = (const float*)d_in[6];
  const float* wo = (const float*)d_in[7];

  char* ws = (char*)d_ws;
  u16* xb    = (u16*)(ws);                    // 8 MB (reused as attn later)
  u16* wqkvT = (u16*)(ws + (8u << 20));       // 10 MB
  u16* woT   = (u16*)(ws + (18u << 20));      // 8 MB
  u16* QKV   = (u16*)(ws + (26u << 20));      // 10 MB
  u16* VT    = (u16*)(ws + (36u << 20));      // 1 MB
  u16* attn  = xb;

  dim3 tb32(32, 8);

  convert_f32_bf16<<<4096, 256, 0, stream>>>(x, xb, 2048 * 2048);
  transpose_f32_bf16<<<dim3(64, 64), tb32, 0, stream>>>(wq, wqkvT, 2048, 2048);
  transpose_f32_bf16<<<dim3(8, 64), tb32, 0, stream>>>(wk, wqkvT + (size_t)2048 * 2048, 2048, 256);
  transpose_f32_bf16<<<dim3(8, 64), tb32, 0, stream>>>(wv, wqkvT + (size_t)2304 * 2048, 2048, 256);
  transpose_f32_bf16<<<dim3(64, 64), tb32, 0, stream>>>(wo, woT, 2048, 2048);

  gemm_bt<false><<<dim3(20, 16), 256, 0, stream>>>(xb, wqkvT, QKV, 2048, 2560, 2048);

  rope_kernel<<<9216, 256, 0, stream>>>(QKV, fcos, fsin);

  transpose_bf16<<<dim3(8, 64), tb32, 0, stream>>>(QKV + 2304, 2560, VT, 2048, 256);

  attn_kernel<<<dim3(32, 32), 256, 0, stream>>>(QKV, VT, attn);

  gemm_bt<true><<<dim3(16, 16), 256, 0, stream>>>(attn, woT, d_out, 2048, 2048, 2048);
}